// Round 1
// baseline (8343.612 us; speedup 1.0000x reference)
//
#include <hip/hip_runtime.h>
#include <math.h>

#define B_ 64
#define T_ 48
#define H_ 512
#define V_ 32000
#define G_ 2048   // 4*H
#define KC 64

__device__ __forceinline__ float sigmoidf_(float x) { return 1.0f / (1.0f + __expf(-x)); }

// ---------------------------------------------------------------------------
// zero-init of chain state (slot 0 of h1/h2 trajectories, c1, c2)
// ---------------------------------------------------------------------------
__global__ void zero_init(float* a, float* b, float* c, float* d) {
    int i = blockIdx.x * 256 + threadIdx.x;           // 64 blocks * 256 = 16384
    for (int k = i; k < B_ * H_; k += 64 * 256) { a[k] = 0.f; b[k] = 0.f; c[k] = 0.f; d[k] = 0.f; }
}

// ---------------------------------------------------------------------------
// One LSTM chain step: gates[b, g*512+j] = sum_k h_in[b,k]*W_h[g*512+j, k]
//                      (+ optional x_in@W_x, + optional pre, + optional biases)
// Block: 4 units (16 gate-cols) x 64 batch. Grid: 128 blocks.
// ---------------------------------------------------------------------------
__global__ __launch_bounds__(256) void lstm_step_kernel(
    const float* __restrict__ h_in,
    const float* __restrict__ W_h,
    const float* __restrict__ x_in, int x_bstride,
    const float* __restrict__ W_x, int x_lda, int x_coff,
    const float* __restrict__ pre,
    const float* __restrict__ bA, const float* __restrict__ bB,
    float* __restrict__ c_st, float* __restrict__ h_out)
{
    __shared__ __align__(16) float in_t[KC][B_ + 1];   // [kk][b]
    __shared__ __align__(16) float w_t[KC][20];        // [kk][c], stride 20 floats (16B-aligned rows)
    __shared__ float gbuf[4][4][B_ + 1];               // [gate][u][b]

    const int tid = threadIdx.x;
    const int j0 = blockIdx.x * 4;
    const int b_t = tid >> 2;
    const int cg = tid & 3;                             // gate this thread accumulates
    float acc0 = 0.f, acc1 = 0.f, acc2 = 0.f, acc3 = 0.f;

    // ---- segment 0: h_in @ W_h ----
    for (int k0 = 0; k0 < H_; k0 += KC) {
        for (int i = tid; i < KC * B_; i += 256) { int bb = i >> 6, kk = i & 63;
            in_t[kk][bb] = h_in[bb * H_ + k0 + kk]; }
        for (int i = tid; i < KC * 16; i += 256) { int c = i >> 6, kk = i & 63;
            int row = (c >> 2) * H_ + j0 + (c & 3);
            w_t[kk][c] = W_h[row * H_ + k0 + kk]; }
        __syncthreads();
#pragma unroll
        for (int kk = 0; kk < KC; ++kk) {
            float iv = in_t[kk][b_t];
            const float4 wv = *reinterpret_cast<const float4*>(&w_t[kk][cg * 4]);
            acc0 += iv * wv.x; acc1 += iv * wv.y; acc2 += iv * wv.z; acc3 += iv * wv.w;
        }
        __syncthreads();
    }
    // ---- segment 1 (optional): x_in @ W_x ----
    if (x_in) {
        for (int k0 = 0; k0 < H_; k0 += KC) {
            for (int i = tid; i < KC * B_; i += 256) { int bb = i >> 6, kk = i & 63;
                in_t[kk][bb] = x_in[bb * x_bstride + k0 + kk]; }
            for (int i = tid; i < KC * 16; i += 256) { int c = i >> 6, kk = i & 63;
                int row = (c >> 2) * H_ + j0 + (c & 3);
                w_t[kk][c] = W_x[row * x_lda + x_coff + k0 + kk]; }
            __syncthreads();
#pragma unroll
            for (int kk = 0; kk < KC; ++kk) {
                float iv = in_t[kk][b_t];
                const float4 wv = *reinterpret_cast<const float4*>(&w_t[kk][cg * 4]);
                acc0 += iv * wv.x; acc1 += iv * wv.y; acc2 += iv * wv.z; acc3 += iv * wv.w;
            }
            __syncthreads();
        }
    }

    // ---- stash gates, then cell update ----
    float a[4] = {acc0, acc1, acc2, acc3};
#pragma unroll
    for (int u = 0; u < 4; ++u) {
        float v = a[u];
        int col = cg * H_ + j0 + u;
        if (pre) v += pre[b_t * G_ + col];
        if (bA) v += bA[col];
        if (bB) v += bB[col];
        gbuf[cg][u][b_t] = v;
    }
    __syncthreads();
    {
        int b = tid >> 2, u = tid & 3;
        int idx = b * H_ + j0 + u;
        float gi = gbuf[0][u][b], gf = gbuf[1][u][b], gg = gbuf[2][u][b], go = gbuf[3][u][b];
        float co = c_st[idx];
        float i_ = sigmoidf_(gi), f_ = sigmoidf_(gf), o_ = sigmoidf_(go);
        float g_ = tanhf(gg);
        float cn = f_ * co + i_ * g_;
        c_st[idx] = cn;
        h_out[idx] = o_ * tanhf(cn);
    }
}

// ---------------------------------------------------------------------------
// Batched layer-2 input projections for all 95 steps:
//   s<48 : Q[s] = h1_all[s+1] @ w_ih2[:,512:].T + (b_ih2 + b_hh2)
//   s>=48: Q[s] = h1_all[s+1] @ w_ihd2[:,512:].T + cap[s-48] @ w_ihd2[:,:512].T + (b_ihd2+b_hhd2)
// Block: 64 b x 32 cols. Grid: (64, 95).
// ---------------------------------------------------------------------------
__global__ __launch_bounds__(256) void qbuild_kernel(
    const float* __restrict__ h1_all, const float* __restrict__ caption,
    const float* __restrict__ w_ih2, const float* __restrict__ b_ih2, const float* __restrict__ b_hh2,
    const float* __restrict__ w_ihd2, const float* __restrict__ b_ihd2, const float* __restrict__ b_hhd2,
    float* __restrict__ Q)
{
    __shared__ __align__(16) float in_t[KC][B_ + 1];
    __shared__ __align__(16) float w_t[KC][36];        // 144B row stride
    const int s = blockIdx.y;
    const int n0 = blockIdx.x * 32;
    const int tid = threadIdx.x;
    const int b_t = tid >> 2, cq = tid & 3;
    const bool dec = (s >= 48);
    const float* W = dec ? w_ihd2 : w_ih2;
    const float* bA = dec ? b_ihd2 : b_ih2;
    const float* bB = dec ? b_hhd2 : b_hh2;
    const float* h1 = h1_all + (s + 1) * (B_ * H_);
    float acc[8] = {0.f, 0.f, 0.f, 0.f, 0.f, 0.f, 0.f, 0.f};

    // segment 1: h1 part (cols 512..1023 of W)
    for (int k0 = 0; k0 < H_; k0 += KC) {
        for (int i = tid; i < KC * B_; i += 256) { int bb = i >> 6, kk = i & 63;
            in_t[kk][bb] = h1[bb * H_ + k0 + kk]; }
        for (int i = tid; i < KC * 32; i += 256) { int c = i >> 6, kk = i & 63;
            w_t[kk][c] = W[(n0 + c) * 1024 + 512 + k0 + kk]; }
        __syncthreads();
#pragma unroll 8
        for (int kk = 0; kk < KC; ++kk) {
            float iv = in_t[kk][b_t];
            const float4 w0 = *reinterpret_cast<const float4*>(&w_t[kk][cq * 8]);
            const float4 w1 = *reinterpret_cast<const float4*>(&w_t[kk][cq * 8 + 4]);
            acc[0] += iv * w0.x; acc[1] += iv * w0.y; acc[2] += iv * w0.z; acc[3] += iv * w0.w;
            acc[4] += iv * w1.x; acc[5] += iv * w1.y; acc[6] += iv * w1.z; acc[7] += iv * w1.w;
        }
        __syncthreads();
    }
    if (dec) {  // segment 2: caption part (cols 0..511)
        const float* cap = caption + (s - 48) * H_;     // b-stride T_*H_
        for (int k0 = 0; k0 < H_; k0 += KC) {
            for (int i = tid; i < KC * B_; i += 256) { int bb = i >> 6, kk = i & 63;
                in_t[kk][bb] = cap[bb * (T_ * H_) + k0 + kk]; }
            for (int i = tid; i < KC * 32; i += 256) { int c = i >> 6, kk = i & 63;
                w_t[kk][c] = W[(n0 + c) * 1024 + k0 + kk]; }
            __syncthreads();
#pragma unroll 8
            for (int kk = 0; kk < KC; ++kk) {
                float iv = in_t[kk][b_t];
                const float4 w0 = *reinterpret_cast<const float4*>(&w_t[kk][cq * 8]);
                const float4 w1 = *reinterpret_cast<const float4*>(&w_t[kk][cq * 8 + 4]);
                acc[0] += iv * w0.x; acc[1] += iv * w0.y; acc[2] += iv * w0.z; acc[3] += iv * w0.w;
                acc[4] += iv * w1.x; acc[5] += iv * w1.y; acc[6] += iv * w1.z; acc[7] += iv * w1.w;
            }
            __syncthreads();
        }
    }
#pragma unroll
    for (int i = 0; i < 8; ++i) {
        int n = n0 + cq * 8 + i;
        Q[(long)s * (B_ * G_) + b_t * G_ + n] = acc[i] + bA[n] + bB[n];
    }
}

// ---------------------------------------------------------------------------
// Fused logits + partial sum-exp + target-logit gather.
// Block: 64 rows (one decoder step) x 128 vocab. Grid: (250, 47).
// ---------------------------------------------------------------------------
__global__ __launch_bounds__(256) void ce_kernel(
    const float* __restrict__ h2_all, const float* __restrict__ w_o,
    const float* __restrict__ b_o, const int* __restrict__ ids,
    float* __restrict__ partial, float* __restrict__ tgt)
{
    __shared__ __align__(16) float in_t[KC][B_ + 1];
    __shared__ __align__(16) float w_t[KC][132];       // 528B row stride (33*16)
    __shared__ float red[B_][8];
    const int vt = blockIdx.x, td = blockIdx.y;
    const int v0 = vt * 128;
    const float* h2 = h2_all + (49 + td) * (B_ * H_);
    const int tid = threadIdx.x;
    const int rg = tid & 31, cgp = tid >> 5;
    float acc[2][16];
#pragma unroll
    for (int h = 0; h < 2; ++h)
#pragma unroll
        for (int j = 0; j < 16; ++j) acc[h][j] = 0.f;

    for (int k0 = 0; k0 < H_; k0 += KC) {
        for (int i = tid; i < KC * B_; i += 256) { int bb = i >> 6, kk = i & 63;
            in_t[kk][bb] = h2[bb * H_ + k0 + kk]; }
        for (int i = tid; i < KC * 128; i += 256) { int c = i >> 6, kk = i & 63;
            w_t[kk][c] = w_o[(v0 + c) * H_ + k0 + kk]; }
        __syncthreads();
#pragma unroll 8
        for (int kk = 0; kk < KC; ++kk) {
            float a0 = in_t[kk][rg], a1 = in_t[kk][rg + 32];
#pragma unroll
            for (int q = 0; q < 4; ++q) {
                const float4 w = *reinterpret_cast<const float4*>(&w_t[kk][cgp * 16 + q * 4]);
                acc[0][q * 4 + 0] += a0 * w.x; acc[0][q * 4 + 1] += a0 * w.y;
                acc[0][q * 4 + 2] += a0 * w.z; acc[0][q * 4 + 3] += a0 * w.w;
                acc[1][q * 4 + 0] += a1 * w.x; acc[1][q * 4 + 1] += a1 * w.y;
                acc[1][q * 4 + 2] += a1 * w.z; acc[1][q * 4 + 3] += a1 * w.w;
            }
        }
        __syncthreads();
    }
    // add b_o, sum-exp (no max shift: |logit| <= ~23, safe in fp32)
    float lg0[16], lg1[16];
    float ls0 = 0.f, ls1 = 0.f;
#pragma unroll
    for (int j = 0; j < 16; ++j) {
        float bo = b_o[v0 + cgp * 16 + j];
        lg0[j] = acc[0][j] + bo; lg1[j] = acc[1][j] + bo;
        ls0 += __expf(lg0[j]); ls1 += __expf(lg1[j]);
    }
    red[rg][cgp] = ls0; red[rg + 32][cgp] = ls1;
    __syncthreads();
    if (tid < 64) {
        float s = 0.f;
#pragma unroll
        for (int i = 0; i < 8; ++i) s += red[tid][i];
        partial[(long)vt * 3008 + td * 64 + tid] = s;
    }
    // target logits (unique writer: the block/thread whose tile holds the target)
    {
        int t0 = ids[rg * T_ + td + 1];
        if (t0 >= v0 && t0 < v0 + 128) { int cl = t0 - v0; if ((cl >> 4) == cgp) tgt[td * 64 + rg] = lg0[cl & 15]; }
        int t1 = ids[(rg + 32) * T_ + td + 1];
        if (t1 >= v0 && t1 < v0 + 128) { int cl = t1 - v0; if ((cl >> 4) == cgp) tgt[td * 64 + rg + 32] = lg1[cl & 15]; }
    }
}

__global__ void ce_combine(const float* __restrict__ partial, const float* __restrict__ tgt,
                           float* __restrict__ ce_row)
{
    int r = blockIdx.x * 256 + threadIdx.x;
    if (r < 3008) {
        float s = 0.f;
        for (int i = 0; i < 250; ++i) s += partial[(long)i * 3008 + r];
        ce_row[r] = __logf(s) - tgt[r];
    }
}

__global__ void ce_final(const float* __restrict__ ce_row, float* __restrict__ out)
{
    __shared__ float red[256];
    float s = 0.f;
    for (int i = threadIdx.x; i < 3008; i += 256) s += ce_row[i];
    red[threadIdx.x] = s;
    __syncthreads();
    for (int off = 128; off > 0; off >>= 1) {
        if (threadIdx.x < off) red[threadIdx.x] += red[threadIdx.x + off];
        __syncthreads();
    }
    if (threadIdx.x == 0) out[0] = red[0] * (1.0f / 4096.0f);
}

// ---------------------------------------------------------------------------
extern "C" void kernel_launch(void* const* d_in, const int* in_sizes, int n_in,
                              void* d_out, int out_size, void* d_ws, size_t ws_size,
                              hipStream_t stream)
{
    const float* feat    = (const float*)d_in[0];
    const float* caption = (const float*)d_in[1];
    const int*   ids     = (const int*)d_in[2];
    const float* w_ih1  = (const float*)d_in[3];
    const float* w_hh1  = (const float*)d_in[4];
    const float* b_ih1  = (const float*)d_in[5];
    const float* b_hh1  = (const float*)d_in[6];
    const float* w_ih2  = (const float*)d_in[7];
    const float* w_hh2  = (const float*)d_in[8];
    const float* b_ih2  = (const float*)d_in[9];
    const float* b_hh2  = (const float*)d_in[10];
    const float* w_ihd1 = (const float*)d_in[11]; (void)w_ihd1;
    const float* w_hhd1 = (const float*)d_in[12];
    const float* b_ihd1 = (const float*)d_in[13];
    const float* b_hhd1 = (const float*)d_in[14];
    const float* w_ihd2 = (const float*)d_in[15];
    const float* w_hhd2 = (const float*)d_in[16];
    const float* b_ihd2 = (const float*)d_in[17];
    const float* b_hhd2 = (const float*)d_in[18];
    const float* w_o    = (const float*)d_in[19];
    const float* b_o    = (const float*)d_in[20];

    const int BH = B_ * H_;                 // 32768
    float* f = (float*)d_ws;
    float* h1_all = f;                      // 96 * 32768
    float* h2_all = h1_all + 96 * BH;       // 96 * 32768
    float* c1 = h2_all + 96 * BH;           // 32768
    float* c2 = c1 + BH;                    // 32768
    float* Q  = c2 + BH;                    // 95 * 64 * 2048
    float* partial = Q + 95L * B_ * G_;     // 250 * 3008
    float* tgt = partial + 250L * 3008;     // 3008
    float* ce_row = tgt + 3008;             // 3008

    zero_init<<<64, 256, 0, stream>>>(h1_all, h2_all, c1, c2);

    // ---- phase A: layer-1 chain (encoder 48 + decoder 47 steps) ----
    for (int s = 0; s < 95; ++s) {
        const float* h_in = h1_all + s * BH;
        float* h_out = h1_all + (s + 1) * BH;
        if (s < 48) {
            lstm_step_kernel<<<128, 256, 0, stream>>>(
                h_in, w_hh1,
                feat + s * H_, T_ * H_, w_ih1, H_, 0,
                nullptr, b_ih1, b_hh1, c1, h_out);
        } else {
            lstm_step_kernel<<<128, 256, 0, stream>>>(
                h_in, w_hhd1,
                nullptr, 0, nullptr, 0, 0,
                nullptr, b_ihd1, b_hhd1, c1, h_out);
        }
    }

    // ---- phase B: batched layer-2 input projections ----
    qbuild_kernel<<<dim3(64, 95), 256, 0, stream>>>(
        h1_all, caption, w_ih2, b_ih2, b_hh2, w_ihd2, b_ihd2, b_hhd2, Q);

    // ---- phase C: layer-2 chain ----
    for (int s = 0; s < 95; ++s) {
        const float* h_in = h2_all + s * BH;
        float* h_out = h2_all + (s + 1) * BH;
        const float* Wh = (s < 48) ? w_hh2 : w_hhd2;
        lstm_step_kernel<<<128, 256, 0, stream>>>(
            h_in, Wh,
            nullptr, 0, nullptr, 0, 0,
            Q + (long)s * (B_ * G_), nullptr, nullptr, c2, h_out);
    }

    // ---- phase D: fused logits + CE ----
    ce_kernel<<<dim3(250, 47), 256, 0, stream>>>(h2_all, w_o, b_o, ids, partial, tgt);
    ce_combine<<<12, 256, 0, stream>>>(partial, tgt, ce_row);
    ce_final<<<1, 256, 0, stream>>>(ce_row, (float*)d_out);
}

// Round 2
// 1915.618 us; speedup vs baseline: 4.3556x; 4.3556x over previous
//
#include <hip/hip_runtime.h>
#include <math.h>

#define B_ 64
#define T_ 48
#define H_ 512
#define V_ 32000
#define G_ 2048

typedef short short8 __attribute__((ext_vector_type(8)));
typedef float f32x4 __attribute__((ext_vector_type(4)));

__device__ __forceinline__ float sigmoidf_(float x){ return 1.f/(1.f+__expf(-x)); }

// fp32 -> bf16 round-to-nearest-even, as bit pattern
__device__ __forceinline__ unsigned short f2bf(float f){
  unsigned u = __float_as_uint(f);
  u += 0x7fffu + ((u>>16)&1u);
  return (unsigned short)(u>>16);
}

// load 8 consecutive fp32, convert to 8 bf16 (as short8)
__device__ __forceinline__ short8 cvt8(const float* g){
  float4 a = *(const float4*)g;
  float4 b = *(const float4*)(g+4);
  short8 v;
  v[0]=(short)f2bf(a.x); v[1]=(short)f2bf(a.y); v[2]=(short)f2bf(a.z); v[3]=(short)f2bf(a.w);
  v[4]=(short)f2bf(b.x); v[5]=(short)f2bf(b.y); v[6]=(short)f2bf(b.z); v[7]=(short)f2bf(b.w);
  return v;
}

// ---------------------------------------------------------------------------
// init: zero h1[0], h2[0] (bf16) and the grid-barrier state
// ---------------------------------------------------------------------------
__global__ void init_kernel(unsigned short* h1_0, unsigned short* h2_0, unsigned* bar){
  int i = blockIdx.x*256 + threadIdx.x;   // 32 blocks -> 8192 threads
  short8 z = {0,0,0,0,0,0,0,0};
  if (i < 4096) ((short8*)h1_0)[i] = z;
  else          ((short8*)h2_0)[i-4096] = z;
  if (i < 8) bar[i] = 0u;
}

// ---------------------------------------------------------------------------
// mm_pre: out[s] = A(s) @ W.T + biases   (M=64, N=2048 in 8 tiles of 256, K=512)
// mode 0: X1 (A = feat fp32), mode 1: Q (A = h1_bf; dec adds caption pass)
// grid (s, ntile), 512 threads = 8 waves, wave n-split 32
// ---------------------------------------------------------------------------
__global__ __launch_bounds__(512,1) void mm_pre_kernel(
    int mode,
    const float* __restrict__ feat, const unsigned short* __restrict__ h1_bf,
    const float* __restrict__ caption,
    const float* __restrict__ w_ih1, const float* __restrict__ b_ih1, const float* __restrict__ b_hh1,
    const float* __restrict__ w_ih2, const float* __restrict__ b_ih2, const float* __restrict__ b_hh2,
    const float* __restrict__ w_ihd2, const float* __restrict__ b_ihd2, const float* __restrict__ b_hhd2,
    float* __restrict__ out)
{
  const int s = blockIdx.x, n0 = blockIdx.y*256;
  const int t = threadIdx.x, w = t>>6, l = t&63, ln = l&15, lk = l>>4;
  __shared__ short8 smA[64*64];    // 64 KB  [64][512] bf16, XOR-swizzled 16B chunks
  __shared__ short8 smB[256*8];    // 32 KB  [256][64] bf16, swizzled

  int npass = 1;
  const float* W; int ld, koff; const float* bA; const float* bB;
  const unsigned short* abf = nullptr; const float* af32 = nullptr; int astr = 0; long aoff = 0;
  if (mode == 0){
    af32 = feat; astr = T_*H_; aoff = (long)s*H_;
    W = w_ih1; ld = H_; koff = 0; bA = b_ih1; bB = b_hh1;
  } else {
    abf = h1_bf + (long)(s+1)*(B_*H_);
    if (s < 48){ W = w_ih2;  ld = 1024; koff = 512; bA = b_ih2;  bB = b_hh2; }
    else       { W = w_ihd2; ld = 1024; koff = 512; bA = b_ihd2; bB = b_hhd2; npass = 2; }
  }

  f32x4 acc[4][2];
#pragma unroll
  for (int mf=0; mf<4; ++mf){
#pragma unroll
    for (int nf=0; nf<2; ++nf) acc[mf][nf] = (f32x4){0.f,0.f,0.f,0.f};
  }

  for (int p=0; p<npass; ++p){
    if (p == 1){ abf = nullptr; af32 = caption; astr = T_*H_; aoff = (long)(s-48)*H_; koff = 0; }
    __syncthreads();
    if (abf){
#pragma unroll
      for (int i=0;i<8;++i){ int e=i*4096+t*8; int m=e>>9, k=e&511;
        smA[m*64 + ((k>>3)^(m&7))] = *(const short8*)(abf + m*512 + k); }
    } else {
#pragma unroll
      for (int i=0;i<8;++i){ int e=i*4096+t*8; int m=e>>9, k=e&511;
        smA[m*64 + ((k>>3)^(m&7))] = cvt8(&af32[(long)m*astr + aoff + k]); }
    }
    for (int kc=0; kc<8; ++kc){
      __syncthreads();
#pragma unroll
      for (int i=0;i<4;++i){ int e=i*4096+t*8; int n=e>>6, k=e&63;
        smB[n*8 + ((k>>3)^(n&7))] = cvt8(&W[(long)(n0+n)*ld + koff + kc*64 + k]); }
      __syncthreads();
#pragma unroll
      for (int ks2=0; ks2<2; ++ks2){
#pragma unroll
        for (int nf=0; nf<2; ++nf){
          int n = w*32 + nf*16 + ln;
          short8 bfr = smB[n*8 + ((ks2*4+lk)^(n&7))];
#pragma unroll
          for (int mf=0; mf<4; ++mf){
            int m = mf*16+ln;
            short8 afr = smA[m*64 + (((kc*2+ks2)*4+lk)^(m&7))];
            acc[mf][nf] = __builtin_amdgcn_mfma_f32_16x16x32_bf16(afr, bfr, acc[mf][nf], 0,0,0);
          }
        }
      }
    }
  }
#pragma unroll
  for (int nf=0; nf<2; ++nf){
    int n = n0 + w*32 + nf*16 + ln;
    float bias = bA[n] + bB[n];
#pragma unroll
    for (int mf=0; mf<4; ++mf){
#pragma unroll
      for (int r=0; r<4; ++r){
        int m = mf*16 + lk*4 + r;
        out[(long)s*(B_*G_) + (long)m*G_ + n] = acc[mf][nf][r] + bias;
      }
    }
  }
}

// ---------------------------------------------------------------------------
// chain: 95 sequential LSTM-cell steps, weights resident in VGPRs (bf16),
// c-state resident in LDS, manual device-scope grid barrier (32 blocks).
// Block bc owns h-cols [bc*16, bc*16+16); wave g = gate g.
// ---------------------------------------------------------------------------
__global__ __launch_bounds__(256,1) void chain_kernel(
    const float* __restrict__ W_enc, const float* __restrict__ W_dec,  // [2048][512] fp32
    const float* __restrict__ pre_all, int pre_count,                  // [S][64][2048] fp32
    const float* __restrict__ bd1, const float* __restrict__ bd2,      // dec biases or null
    unsigned short* __restrict__ h_all,                                // [96][64][512] bf16
    unsigned* bar)
{
  const int t = threadIdx.x, bc = blockIdx.x;
  const int g = t>>6, l = t&63, ln = l&15, lk = l>>4;
  __shared__ short8 smA[64*64];          // 64 KB h staging
  __shared__ float gbuf[4][16][68];      // [gate][n][m] fp32
  __shared__ float c_lds[16][68];        // [n][m]

  short8 Be[16], Bd[16];
  const long wrow = (long)(g*512 + bc*16 + ln) * 512;
#pragma unroll
  for (int ks=0; ks<16; ++ks){
    Be[ks] = cvt8(&W_enc[wrow + ks*32 + lk*8]);
    Bd[ks] = cvt8(&W_dec[wrow + ks*32 + lk*8]);
  }
  float biasd = 0.f;
  if (bd1) biasd = bd1[g*512+bc*16+ln] + bd2[g*512+bc*16+ln];

  for (int i=t; i<16*68; i+=256) (&c_lds[0][0])[i] = 0.f;

  for (int s=0; s<95; ++s){
    __syncthreads();
    { const unsigned short* hp = h_all + (long)s*(B_*H_);
#pragma unroll
      for (int i=0;i<8;++i){ int e=i*2048+t*8; int m=e>>9, k=e&511;
        smA[m*64 + ((k>>3)^(m&7))] = *(const short8*)(hp + m*512 + k); } }
    __syncthreads();

    f32x4 acc[4];
#pragma unroll
    for (int mf=0; mf<4; ++mf) acc[mf] = (f32x4){0.f,0.f,0.f,0.f};

    if (s < 48){
#pragma unroll
      for (int ks=0; ks<16; ++ks){
#pragma unroll
        for (int mf=0; mf<4; ++mf){
          int m = mf*16+ln;
          short8 af = smA[m*64 + ((ks*4+lk)^(m&7))];
          acc[mf] = __builtin_amdgcn_mfma_f32_16x16x32_bf16(af, Be[ks], acc[mf], 0,0,0);
        }
      }
    } else {
#pragma unroll
      for (int ks=0; ks<16; ++ks){
#pragma unroll
        for (int mf=0; mf<4; ++mf){
          int m = mf*16+ln;
          short8 af = smA[m*64 + ((ks*4+lk)^(m&7))];
          acc[mf] = __builtin_amdgcn_mfma_f32_16x16x32_bf16(af, Bd[ks], acc[mf], 0,0,0);
        }
      }
    }

    if (s < pre_count){
      const float* pp = pre_all + (long)s*(B_*G_) + g*512 + bc*16 + ln;
#pragma unroll
      for (int mf=0; mf<4; ++mf){
#pragma unroll
        for (int r=0;r<4;++r)
          acc[mf][r] += pp[(long)(mf*16 + lk*4 + r)*G_];
      }
    } else {
#pragma unroll
      for (int mf=0; mf<4; ++mf){
#pragma unroll
        for (int r=0;r<4;++r) acc[mf][r] += biasd;
      }
    }

#pragma unroll
    for (int mf=0; mf<4; ++mf)
      *(f32x4*)&gbuf[g][ln][mf*16 + lk*4] = acc[mf];
    __syncthreads();

    { int n = t&15, m0 = (t>>4)*4;
      float4 gi = *(float4*)&gbuf[0][n][m0];
      float4 gf = *(float4*)&gbuf[1][n][m0];
      float4 gg = *(float4*)&gbuf[2][n][m0];
      float4 go = *(float4*)&gbuf[3][n][m0];
      float4 c4 = *(float4*)&c_lds[n][m0];
      unsigned short* ho = h_all + (long)(s+1)*(B_*H_) + bc*16 + n;
      float ci[4]={c4.x,c4.y,c4.z,c4.w};
      float a_i[4]={gi.x,gi.y,gi.z,gi.w}, a_f[4]={gf.x,gf.y,gf.z,gf.w};
      float a_g[4]={gg.x,gg.y,gg.z,gg.w}, a_o[4]={go.x,go.y,go.z,go.w};
      float cn[4], hv[4];
#pragma unroll
      for (int j=0;j<4;++j){
        float i_ = sigmoidf_(a_i[j]), f_ = sigmoidf_(a_f[j]), o_ = sigmoidf_(a_o[j]);
        float g_ = tanhf(a_g[j]);
        cn[j] = f_*ci[j] + i_*g_;
        hv[j] = o_*tanhf(cn[j]);
      }
      *(float4*)&c_lds[n][m0] = make_float4(cn[0],cn[1],cn[2],cn[3]);
#pragma unroll
      for (int j=0;j<4;++j) ho[(long)(m0+j)*512] = f2bf(hv[j]);
    }

    // -------- device-scope grid barrier over 32 co-resident blocks --------
    __syncthreads();
    if (t == 0){
      __threadfence();
      unsigned gen = __hip_atomic_load(&bar[1], __ATOMIC_RELAXED, __HIP_MEMORY_SCOPE_AGENT);
      unsigned a = __hip_atomic_fetch_add(&bar[0], 1u, __ATOMIC_ACQ_REL, __HIP_MEMORY_SCOPE_AGENT);
      if (a == 31u){
        __hip_atomic_store(&bar[0], 0u, __ATOMIC_RELAXED, __HIP_MEMORY_SCOPE_AGENT);
        __hip_atomic_fetch_add(&bar[1], 1u, __ATOMIC_RELEASE, __HIP_MEMORY_SCOPE_AGENT);
      } else {
        while (__hip_atomic_load(&bar[1], __ATOMIC_ACQUIRE, __HIP_MEMORY_SCOPE_AGENT) == gen)
          __builtin_amdgcn_s_sleep(1);
      }
      __threadfence();
    }
    __syncthreads();
  }
}

// ---------------------------------------------------------------------------
// CE: logits (bf16 MFMA) + sum-exp partials + target-logit gather
// grid (td 47, vt 125), 512 threads, M=64 N=256 K=512
// ---------------------------------------------------------------------------
__global__ __launch_bounds__(512,1) void ce_mfma_kernel(
    const unsigned short* __restrict__ h2_bf, const float* __restrict__ w_o,
    const float* __restrict__ b_o, const int* __restrict__ ids,
    float* __restrict__ partial, float* __restrict__ tgt)
{
  const int td = blockIdx.x, vt = blockIdx.y, v0 = vt*256;
  const int t = threadIdx.x, w = t>>6, l = t&63, ln = l&15, lk = l>>4;
  __shared__ short8 smA[64*64];
  __shared__ short8 smB[256*8];
  __shared__ float red[8][64];
  __shared__ int tid_s[64];

  const unsigned short* hp = h2_bf + (long)(49+td)*(B_*H_);
  if (t < 64) tid_s[t] = ids[t*T_ + td + 1];
#pragma unroll
  for (int i=0;i<8;++i){ int e=i*4096+t*8; int m=e>>9, k=e&511;
    smA[m*64 + ((k>>3)^(m&7))] = *(const short8*)(hp + m*512 + k); }

  f32x4 acc[4][2];
#pragma unroll
  for (int mf=0; mf<4; ++mf){
#pragma unroll
    for (int nf=0; nf<2; ++nf) acc[mf][nf] = (f32x4){0.f,0.f,0.f,0.f};
  }

  for (int kc=0; kc<8; ++kc){
    __syncthreads();
#pragma unroll
    for (int i=0;i<4;++i){ int e=i*4096+t*8; int n=e>>6, k=e&63;
      smB[n*8 + ((k>>3)^(n&7))] = cvt8(&w_o[(long)(v0+n)*512 + kc*64 + k]); }
    __syncthreads();
#pragma unroll
    for (int ks2=0; ks2<2; ++ks2){
#pragma unroll
      for (int nf=0; nf<2; ++nf){
        int n = w*32 + nf*16 + ln;
        short8 bfr = smB[n*8 + ((ks2*4+lk)^(n&7))];
#pragma unroll
        for (int mf=0; mf<4; ++mf){
          int m = mf*16+ln;
          short8 afr = smA[m*64 + (((kc*2+ks2)*4+lk)^(m&7))];
          acc[mf][nf] = __builtin_amdgcn_mfma_f32_16x16x32_bf16(afr, bfr, acc[mf][nf], 0,0,0);
        }
      }
    }
  }

  float se[4][4];
#pragma unroll
  for (int mf=0; mf<4; ++mf){
#pragma unroll
    for (int r=0;r<4;++r) se[mf][r] = 0.f;
  }
#pragma unroll
  for (int nf=0; nf<2; ++nf){
    int ng = v0 + w*32 + nf*16 + ln;
    float bo = b_o[ng];
#pragma unroll
    for (int mf=0; mf<4; ++mf){
#pragma unroll
      for (int r=0;r<4;++r){
        int m = mf*16 + lk*4 + r;
        float lg = acc[mf][nf][r] + bo;
        se[mf][r] += __expf(lg);
        if (ng == tid_s[m]) tgt[td*64 + m] = lg;
      }
    }
  }
#pragma unroll
  for (int off=1; off<16; off<<=1){
#pragma unroll
    for (int mf=0; mf<4; ++mf){
#pragma unroll
      for (int r=0;r<4;++r) se[mf][r] += __shfl_xor(se[mf][r], off);
    }
  }
  if (ln == 0){
#pragma unroll
    for (int mf=0; mf<4; ++mf)
      *(f32x4*)&red[w][mf*16 + lk*4] = (f32x4){se[mf][0],se[mf][1],se[mf][2],se[mf][3]};
  }
  __syncthreads();
  if (t < 64){
    float ssum = 0.f;
#pragma unroll
    for (int w2=0; w2<8; ++w2) ssum += red[w2][t];
    partial[(long)vt*3008 + td*64 + t] = ssum;
  }
}

__global__ void ce_combine(const float* __restrict__ partial, const float* __restrict__ tgt,
                           float* __restrict__ ce_row){
  int r = blockIdx.x*256 + threadIdx.x;
  if (r < 3008){
    float s = 0.f;
    for (int i=0;i<125;++i) s += partial[(long)i*3008 + r];
    ce_row[r] = __logf(s) - tgt[r];
  }
}

__global__ void ce_final(const float* __restrict__ ce_row, float* __restrict__ out){
  __shared__ float red[256];
  float s = 0.f;
  for (int i=threadIdx.x; i<3008; i+=256) s += ce_row[i];
  red[threadIdx.x] = s;
  __syncthreads();
  for (int off=128; off>0; off>>=1){
    if (threadIdx.x < off) red[threadIdx.x] += red[threadIdx.x + off];
    __syncthreads();
  }
  if (threadIdx.x == 0) out[0] = red[0] * (1.0f/4096.0f);
}

// ---------------------------------------------------------------------------
extern "C" void kernel_launch(void* const* d_in, const int* in_sizes, int n_in,
                              void* d_out, int out_size, void* d_ws, size_t ws_size,
                              hipStream_t stream)
{
  (void)in_sizes; (void)n_in; (void)out_size; (void)ws_size;
  const float* feat    = (const float*)d_in[0];
  const float* caption = (const float*)d_in[1];
  const int*   ids     = (const int*)d_in[2];
  const float* w_ih1  = (const float*)d_in[3];
  const float* w_hh1  = (const float*)d_in[4];
  const float* b_ih1  = (const float*)d_in[5];
  const float* b_hh1  = (const float*)d_in[6];
  const float* w_ih2  = (const float*)d_in[7];
  const float* w_hh2  = (const float*)d_in[8];
  const float* b_ih2  = (const float*)d_in[9];
  const float* b_hh2  = (const float*)d_in[10];
  const float* w_hhd1 = (const float*)d_in[12];
  const float* b_ihd1 = (const float*)d_in[13];
  const float* b_hhd1 = (const float*)d_in[14];
  const float* w_ihd2 = (const float*)d_in[15];
  const float* w_hhd2 = (const float*)d_in[16];
  const float* b_ihd2 = (const float*)d_in[17];
  const float* b_hhd2 = (const float*)d_in[18];
  const float* w_o    = (const float*)d_in[19];
  const float* b_o    = (const float*)d_in[20];

  // workspace layout (bytes): h1_bf 6.29MB | h2_bf 6.29MB | qx 49.8MB | partial | tgt | ce_row | bar
  unsigned short* h1_bf = (unsigned short*)d_ws;                       // 96*64*512 bf16
  unsigned short* h2_bf = h1_bf + 96L*B_*H_;
  float* qx     = (float*)((char*)d_ws + 2L*96*B_*H_*2);               // 95*64*2048 fp32 (X1 aliases first 48 slots)
  float* partial= qx + 95L*B_*G_;                                      // 125*3008
  float* tgt    = partial + 125L*3008;                                 // 3008
  float* ce_row = tgt + 3008;                                          // 3008
  unsigned* bar = (unsigned*)(ce_row + 3008);                          // 8 u32

  init_kernel<<<32, 256, 0, stream>>>(h1_bf, h2_bf, bar);

  // X1[s] = feat_s @ w_ih1.T + b_ih1 + b_hh1   (48 steps, aliased into qx)
  mm_pre_kernel<<<dim3(48,8), 512, 0, stream>>>(
      0, feat, nullptr, nullptr,
      w_ih1, b_ih1, b_hh1, w_ih2, b_ih2, b_hh2, w_ihd2, b_ihd2, b_hhd2, qx);

  // layer-1 chain
  chain_kernel<<<32, 256, 0, stream>>>(
      w_hh1, w_hhd1, qx, 48, b_ihd1, b_hhd1, h1_bf, bar);

  // Q[s] = h1[s+1] @ w_ih2/ihd2[:,512:].T (+ cap @ w_ihd2[:,:512].T) + biases
  mm_pre_kernel<<<dim3(95,8), 512, 0, stream>>>(
      1, nullptr, h1_bf, caption,
      w_ih1, b_ih1, b_hh1, w_ih2, b_ih2, b_hh2, w_ihd2, b_ihd2, b_hhd2, qx);

  // layer-2 chain
  chain_kernel<<<32, 256, 0, stream>>>(
      w_hh2, w_hhd2, qx, 95, nullptr, nullptr, h2_bf, bar);

  // CE
  ce_mfma_kernel<<<dim3(47,125), 512, 0, stream>>>(h2_bf, w_o, b_o, ids, partial, tgt);
  ce_combine<<<12, 256, 0, stream>>>(partial, tgt, ce_row);
  ce_final<<<1, 256, 0, stream>>>(ce_row, (float*)d_out);
}